// Round 17
// baseline (44.632 us; speedup 1.0000x reference)
//
#include <hip/hip_runtime.h>
#include <hip/hip_bf16.h>

static constexpr int kC = 256;
static constexpr int kN = 1024;   // H*W

using s16x8 = __attribute__((ext_vector_type(8))) short;
using f32x4 = __attribute__((ext_vector_type(4))) float;
using u32x4 = __attribute__((ext_vector_type(4))) unsigned int;

__device__ inline f32x4 mfma16(s16x8 a, s16x8 b, f32x4 c) {
  return __builtin_amdgcn_mfma_f32_16x16x32_bf16(a, b, c, 0, 0, 0);
}

__device__ inline unsigned short f2bf(float f) {   // RNE
  unsigned u = __builtin_bit_cast(unsigned, f);
  u = (u + 0x7fffu + ((u >> 16) & 1u)) >> 16;
  return (unsigned short)u;
}

__device__ inline float exp2_fast(float x) {   // 2^x, single v_exp_f32
  float r;
  asm("v_exp_f32 %0, %1" : "=v"(r) : "v"(x));
  return r;
}

__device__ inline unsigned cvt_pk_bf16(float lo, float hi) {
  unsigned r;
  asm("v_cvt_pk_bf16_f32 %0, %1, %2" : "=v"(r) : "v"(lo), "v"(hi));
  return r;
}

// 1/sqrt(64) * log2(e): folded into Q so QK^T lands in exp2 units.
static constexpr float kQScale = 0.18033688011112042f;

// ---------------------------------------------------------------------------
// prep: blocks 0..127 pack weights into A-frag layout; blocks 128..383 GN.
// ---------------------------------------------------------------------------
__global__ __launch_bounds__(256) void prep_kernel(
    const float* __restrict__ x, const float* __restrict__ gamma,
    const float* __restrict__ beta, unsigned short* __restrict__ hTp,
    const float* __restrict__ wq, const float* __restrict__ wp,
    unsigned short* __restrict__ Wqp, unsigned short* __restrict__ Wpp) {
  if (blockIdx.x < 128) {
    const int tid = blockIdx.x * 256 + threadIdx.x;   // 0..32767
    const float* src;
    unsigned short* dst;
    if (tid < 24576) {
      const int fragid = tid >> 6, lane = tid & 63;
      const int Mt = fragid >> 3, kt = fragid & 7;
      src = wq + (size_t)(Mt * 16 + (lane & 15)) * 256 + kt * 32 + (lane >> 4) * 8;
      dst = Wqp + (size_t)tid * 8;
    } else {
      const int id = tid - 24576;
      const int fragid = id >> 6, lane = id & 63;
      const int Mt = fragid >> 3, kt = fragid & 7;
      src = wp + (size_t)(Mt * 16 + (lane & 15)) * 256 + kt * 32 + (lane >> 4) * 8;
      dst = Wpp + (size_t)id * 8;
    }
    const float4 f0 = *(const float4*)src;
    const float4 f1 = *(const float4*)(src + 4);
    ushort4 o0, o1;
    o0.x = f2bf(f0.x); o0.y = f2bf(f0.y); o0.z = f2bf(f0.z); o0.w = f2bf(f0.w);
    o1.x = f2bf(f1.x); o1.y = f2bf(f1.y); o1.z = f2bf(f1.z); o1.w = f2bf(f1.w);
    *(ushort4*)dst = o0;
    *(ushort4*)(dst + 4) = o1;
    return;
  }

  const int bg = blockIdx.x - 128;
  const int b = bg & 7, g = bg >> 3;   // batch = XCD
  const size_t base = ((size_t)b * kC + (size_t)g * 8) * kN;
  const float4* __restrict__ x4 = (const float4*)(x + base);
  const int t = threadIdx.x;

  float vv[8][4];
  float s = 0.f, ss = 0.f;
#pragma unroll
  for (int i = 0; i < 8; ++i) {
    const float4 v = x4[t + 256 * i];
    vv[i][0] = v.x; vv[i][1] = v.y; vv[i][2] = v.z; vv[i][3] = v.w;
    s += v.x + v.y + v.z + v.w;
    ss += v.x * v.x + v.y * v.y + v.z * v.z + v.w * v.w;
  }
#pragma unroll
  for (int off = 32; off > 0; off >>= 1) {
    s += __shfl_xor(s, off);
    ss += __shfl_xor(ss, off);
  }
  __shared__ float rs[4], rss[4];
  const int wave = t >> 6, lane = t & 63;
  if (lane == 0) { rs[wave] = s; rss[wave] = ss; }
  __syncthreads();
  s = rs[0] + rs[1] + rs[2] + rs[3];
  ss = rss[0] + rss[1] + rss[2] + rss[3];
  const float mean = s * (1.f / 8192.f);
  const float var = ss * (1.f / 8192.f) - mean * mean;
  const float rinv = rsqrtf(var + 1e-5f);
  float ga[8], be[8];
#pragma unroll
  for (int i = 0; i < 8; ++i) {
    ga[i] = gamma[g * 8 + i] * rinv;
    be[i] = beta[g * 8 + i] - mean * ga[i];
  }
  const int kt = g >> 2, gq = g & 3;
#pragma unroll
  for (int r = 0; r < 4; ++r) {
    const int pos = 4 * t + r;
    const int nt = pos >> 4, lp = pos & 15;
    unsigned short* dst =
        hTp + ((size_t)((b * 64 + nt) * 8 + kt) * 64 + (gq * 16 + lp)) * 8;
    ushort4 o0, o1;
    o0.x = f2bf(vv[0][r] * ga[0] + be[0]);
    o0.y = f2bf(vv[1][r] * ga[1] + be[1]);
    o0.z = f2bf(vv[2][r] * ga[2] + be[2]);
    o0.w = f2bf(vv[3][r] * ga[3] + be[3]);
    o1.x = f2bf(vv[4][r] * ga[4] + be[4]);
    o1.y = f2bf(vv[5][r] * ga[5] + be[5]);
    o1.z = f2bf(vv[6][r] * ga[6] + be[6]);
    o1.w = f2bf(vv[7][r] * ga[7] + be[7]);
    *(ushort4*)dst = o0;
    *(ushort4*)(dst + 4) = o1;
  }
}

// ---------------------------------------------------------------------------
// 64x64 (K=256) tile helpers: per wave 32m x 32n, acc[2][2].
// ---------------------------------------------------------------------------
__device__ inline void gload2(const s16x8* __restrict__ Af,
                              const s16x8* __restrict__ Bf,
                              int Mt0, int Nt0, int kt, int lane,
                              s16x8 (&a)[2], s16x8 (&bb)[2]) {
#pragma unroll
  for (int mt = 0; mt < 2; ++mt)
    a[mt] = Af[((size_t)(Mt0 + mt) * 8 + kt) * 64 + lane];
#pragma unroll
  for (int nt = 0; nt < 2; ++nt)
    bb[nt] = Bf[((size_t)(Nt0 + nt) * 8 + kt) * 64 + lane];
}

__device__ inline void gmfma2(const s16x8 (&a)[2], const s16x8 (&bb)[2],
                              f32x4 (&acc)[2][2], bool swap) {
  if (swap) {
#pragma unroll
    for (int mt = 0; mt < 2; ++mt)
#pragma unroll
      for (int nt = 0; nt < 2; ++nt)
        acc[mt][nt] = mfma16(bb[nt], a[mt], acc[mt][nt]);
  } else {
#pragma unroll
    for (int mt = 0; mt < 2; ++mt)
#pragma unroll
      for (int nt = 0; nt < 2; ++nt)
        acc[mt][nt] = mfma16(a[mt], bb[nt], acc[mt][nt]);
  }
}

// ---------------------------------------------------------------------------
// Fused QKV-GEMM -> fence-free XCD-local wait -> K-split attention -> proj.
// 256 blocks x 512 thr (1 block/CU, all co-resident). b = bid&7 = XCD,
// u = bid>>3 (0..31).
//  phase Q: 6x 64x64 QKV tiles (two 4-wave teams x 3); stores land in the
//           LOCAL (write-back) L2. __syncthreads drains vmcnt. Relaxed
//           agent atomicAdd on cnt[b]; spin to 32. NO cache fence: consumer
//           is same-XCD (b=bid&7 round-robin), L1 was invalidated at kernel
//           entry and never holds these lines -> L2 hit sees dirty data.
//  phase A: R15's 32q/wave K-split attention + merge + fused proj.
// ---------------------------------------------------------------------------
__global__ __launch_bounds__(512) void fused_kernel(
    const unsigned short* __restrict__ Wqp, const float* __restrict__ bq,
    const unsigned short* __restrict__ hTp,
    unsigned short* __restrict__ Qp, unsigned short* __restrict__ Kp,
    unsigned short* __restrict__ Vp,
    const unsigned short* __restrict__ Wpp, const float* __restrict__ bpj,
    const float* __restrict__ x, float* __restrict__ out,
    unsigned* __restrict__ cnt) {
  __shared__ __align__(16) float Ml[4][2][64][18];           // 36 KB partials
  __shared__ __align__(16) unsigned short Ex[2][8][64][8];   // 16 KB proj B-frags
  const int bid = blockIdx.x;
  const int b = bid & 7;          // batch = XCD
  const int u = bid >> 3;         // 0..31
  const int t = threadIdx.x;
  const int w8 = t >> 6, lane = t & 63;
  const int li = lane & 15, grp = lane >> 4;

  // ============ phase Q: QKV GEMM, 6 tiles of 64x64 ============
  {
    const int tm = w8 >> 2, wv = w8 & 3;      // team, wave-in-team
    const int wm = wv >> 1, wn = wv & 1;
    const s16x8* __restrict__ Af = (const s16x8*)Wqp;
    const s16x8* __restrict__ Bf = (const s16x8*)hTp;
#pragma unroll 1
    for (int p = 0; p < 3; ++p) {
      const int r = p * 64 + tm * 32 + u;    // 0..191
      const int mb = r >> 4, nb = r & 15;    // mb 0..11
      const int m0 = mb * 64 + wm * 32;
      const int n0 = nb * 64 + wn * 32;
      const int Mt0 = m0 >> 4;
      const int Nt0 = b * 64 + (n0 >> 4);
      const bool swap = mb >= 8;             // V tiles
      f32x4 acc[2][2];
#pragma unroll
      for (int mt = 0; mt < 2; ++mt)
#pragma unroll
        for (int nt = 0; nt < 2; ++nt) acc[mt][nt] = f32x4{0.f, 0.f, 0.f, 0.f};
      s16x8 aA[2], bA[2], aB[2], bB[2];
      gload2(Af, Bf, Mt0, Nt0, 0, lane, aA, bA);
#pragma unroll
      for (int kt = 0; kt < 8; kt += 2) {
        gload2(Af, Bf, Mt0, Nt0, kt + 1, lane, aB, bB);
        gmfma2(aA, bA, acc, swap);
        if (kt + 2 < 8) gload2(Af, Bf, Mt0, Nt0, kt + 2, lane, aA, bA);
        gmfma2(aB, bB, acc, swap);
      }

      if (!swap) {
        // Q/K: D rows = ch (4grp+rr), cols = pos (li); Q gets kQScale.
        unsigned short* __restrict__ Tp = (mb < 4) ? Qp : Kp;
        const float qs = (mb < 4) ? kQScale : 1.0f;
#pragma unroll
        for (int mt = 0; mt < 2; ++mt) {
          const int mbase = m0 + mt * 16;
          const int head = (mbase >> 6) & 3;
          const int bh = b * 4 + head;
          const int c16 = mbase & 63;
          const int ks = c16 >> 5;
          const int grpp = ((c16 >> 3) + (grp >> 1)) & 3;
          const float4 bv = *(const float4*)(bq + mbase + 4 * grp);
#pragma unroll
          for (int nt = 0; nt < 2; ++nt) {
            const int pt = (n0 >> 4) + nt;
            ushort4 o;
            o.x = f2bf((acc[mt][nt][0] + bv.x) * qs);
            o.y = f2bf((acc[mt][nt][1] + bv.y) * qs);
            o.z = f2bf((acc[mt][nt][2] + bv.z) * qs);
            o.w = f2bf((acc[mt][nt][3] + bv.w) * qs);
            *(ushort4*)(Tp + (size_t)bh * 65536 +
                        ((size_t)(pt * 2 + ks) * 64 + grpp * 16 + li) * 8 +
                        (grp & 1) * 4) = o;
          }
        }
      } else {
        // V: D rows = pos (4grp+rr), cols = ch (li); sigma-permuted store.
#pragma unroll
        for (int mt = 0; mt < 2; ++mt) {
          const int mbase = m0 + mt * 16;
          const int head = (mbase >> 6) & 3;
          const int bh = b * 4 + head;
          const int ct = (mbase & 63) >> 4;
          const float bvc = bq[mbase + li];
          const int kvt = n0 >> 5;
#pragma unroll
          for (int nt = 0; nt < 2; ++nt) {
            ushort4 o;
            o.x = f2bf(acc[mt][nt][0] + bvc);
            o.y = f2bf(acc[mt][nt][1] + bvc);
            o.z = f2bf(acc[mt][nt][2] + bvc);
            o.w = f2bf(acc[mt][nt][3] + bvc);
            *(ushort4*)(Vp + (size_t)bh * 65536 +
                        ((size_t)(ct * 32 + kvt) * 64 + grp * 16 + li) * 8 +
                        nt * 4) = o;
          }
        }
      }
    }
  }

  // ============ fence-free XCD-local publish + wait ============
  __syncthreads();   // drains vmcnt -> stores visible in this XCD's L2
  if (t == 0) {
    __hip_atomic_fetch_add(&cnt[b], 1u, __ATOMIC_RELAXED,
                           __HIP_MEMORY_SCOPE_AGENT);
    while (__hip_atomic_load(&cnt[b], __ATOMIC_RELAXED,
                             __HIP_MEMORY_SCOPE_AGENT) < 32u)
      __builtin_amdgcn_s_sleep(8);
  }
  __syncthreads();   // orders all consumer loads after the spin

  // ============ phase A: K-split attention + proj (R15 body, pb = u) ======
  const int pb = u;
  const int head = w8 & 3, khalf = w8 >> 2;
  const int bh = b * 4 + head;
  const unsigned short* __restrict__ Qb = Qp + (size_t)bh * 65536;
  const unsigned short* __restrict__ Kb = Kp + (size_t)bh * 65536;
  const unsigned short* __restrict__ Vb = Vp + (size_t)bh * 65536;

  s16x8 qf[2][2];
#pragma unroll
  for (int qh = 0; qh < 2; ++qh)
#pragma unroll
    for (int ks = 0; ks < 2; ++ks)
      qf[qh][ks] = *(const s16x8*)(Qb + (((pb * 2 + qh) * 2 + ks) * 64 + lane) * 8);

  f32x4 O[2][4];
  f32x4 lvec[2];
  float m_run[2] = {-1.0e30f, -1.0e30f};
#pragma unroll
  for (int qh = 0; qh < 2; ++qh) {
    lvec[qh] = f32x4{0.f, 0.f, 0.f, 0.f};
#pragma unroll
    for (int ct = 0; ct < 4; ++ct) O[qh][ct] = f32x4{0.f, 0.f, 0.f, 0.f};
  }
  const int kbase = khalf * 16;

  auto loadK = [&](int it, s16x8 (&kk)[2][2]) {
#pragma unroll
    for (int mt = 0; mt < 2; ++mt)
#pragma unroll
      for (int ks = 0; ks < 2; ++ks)
        kk[mt][ks] = *(const s16x8*)(
            Kb + ((size_t)((it * 2 + mt) * 2 + ks) * 64 + lane) * 8);
  };
  auto loadV = [&](int it, s16x8 (&vv)[4]) {
#pragma unroll
    for (int ct = 0; ct < 4; ++ct)
      vv[ct] = *(const s16x8*)(Vb + ((size_t)(ct * 32 + it) * 64 + lane) * 8);
  };

  auto body = [&](const s16x8 (&kk)[2][2], const s16x8 (&vv)[4]) {
    f32x4 s[2][2];
    __builtin_amdgcn_s_setprio(1);
#pragma unroll
    for (int qh = 0; qh < 2; ++qh)
#pragma unroll
      for (int mt = 0; mt < 2; ++mt) {
        s[qh][mt] = mfma16(kk[mt][0], qf[qh][0], f32x4{0.f, 0.f, 0.f, 0.f});
        s[qh][mt] = mfma16(kk[mt][1], qf[qh][1], s[qh][mt]);
      }
    __builtin_amdgcn_s_setprio(0);
#pragma unroll
    for (int qh = 0; qh < 2; ++qh) {
      const float A = fmaxf(fmaxf(s[qh][0][0], s[qh][0][1]), s[qh][0][2]);
      const float B = fmaxf(fmaxf(s[qh][0][3], s[qh][1][0]), s[qh][1][1]);
      const float C = fmaxf(fmaxf(s[qh][1][2], s[qh][1][3]), A);
      float pm = fmaxf(B, C);
      pm = fmaxf(pm, __shfl_xor(pm, 16));
      pm = fmaxf(pm, __shfl_xor(pm, 32));
      if (!__all(pm <= m_run[qh] + 8.0f)) {   // defer-max rescale (exp2 units)
        const float mnew = fmaxf(m_run[qh], pm);
        const float f = exp2_fast(m_run[qh] - mnew);
        m_run[qh] = mnew;
        lvec[qh] *= f;
#pragma unroll
        for (int ct = 0; ct < 4; ++ct) O[qh][ct] *= f;
      }
      f32x4 p[2];
#pragma unroll
      for (int mt = 0; mt < 2; ++mt) {
#pragma unroll
        for (int r = 0; r < 4; ++r) p[mt][r] = exp2_fast(s[qh][mt][r] - m_run[qh]);
        lvec[qh] += p[mt];
      }
      u32x4 pk;
      pk[0] = cvt_pk_bf16(p[0][0], p[0][1]);
      pk[1] = cvt_pk_bf16(p[0][2], p[0][3]);
      pk[2] = cvt_pk_bf16(p[1][0], p[1][1]);
      pk[3] = cvt_pk_bf16(p[1][2], p[1][3]);
      const s16x8 pf = __builtin_bit_cast(s16x8, pk);
      __builtin_amdgcn_s_setprio(1);
#pragma unroll
      for (int ct = 0; ct < 4; ++ct) O[qh][ct] = mfma16(vv[ct], pf, O[qh][ct]);
      __builtin_amdgcn_s_setprio(0);
    }
  };

  {
    s16x8 k0[2][2], k1[2][2], v0[4], v1[4];
    loadK(kbase, k0);
    loadV(kbase, v0);
    // Tail overreads (it = kbase+16) land in adjacent allocated regions —
    // loaded but never consumed arithmetically.
#pragma unroll 1
    for (int h2 = 0; h2 < 8; ++h2) {
      const int it = kbase + 2 * h2;
      loadK(it + 1, k1);
      loadV(it + 1, v1);
      body(k0, v0);
      loadK(it + 2, k0);
      loadV(it + 2, v0);
      body(k1, v1);
    }
  }

  float lt[2];
#pragma unroll
  for (int qh = 0; qh < 2; ++qh) {
    lt[qh] = lvec[qh][0] + lvec[qh][1] + lvec[qh][2] + lvec[qh][3];
    lt[qh] += __shfl_xor(lt[qh], 16);
    lt[qh] += __shfl_xor(lt[qh], 32);
  }

  // ---- merge K-halves per head ----
  if (khalf == 1) {
#pragma unroll
    for (int qh = 0; qh < 2; ++qh) {
      float* dst = &Ml[head][qh][lane][0];
#pragma unroll
      for (int ct = 0; ct < 4; ++ct) *(f32x4*)(dst + ct * 4) = O[qh][ct];
      dst[16] = m_run[qh];
      dst[17] = lt[qh];
    }
  }
  __syncthreads();
  if (khalf == 0) {
#pragma unroll
    for (int qh = 0; qh < 2; ++qh) {
      const float* src = &Ml[head][qh][lane][0];
      const float mB = src[16], lB = src[17];
      const float mS = fmaxf(m_run[qh], mB);
      const float fA = exp2_fast(m_run[qh] - mS);
      const float fB = exp2_fast(mB - mS);
      const float rinv = 1.f / (lt[qh] * fA + lB * fB);
      const float a = fA * rinv, bs = fB * rinv;
#pragma unroll
      for (int ct = 0; ct < 4; ++ct) {
        const f32x4 ob = *(const f32x4*)(src + ct * 4);
        ushort4 o;
        o.x = f2bf(O[qh][ct][0] * a + ob[0] * bs);
        o.y = f2bf(O[qh][ct][1] * a + ob[1] * bs);
        o.z = f2bf(O[qh][ct][2] * a + ob[2] * bs);
        o.w = f2bf(O[qh][ct][3] * a + ob[3] * bs);
        const int ktp = head * 2 + (ct >> 1);
        const int grpp = ((ct & 1) * 2 + (grp >> 1)) & 3;
        *(ushort4*)&Ex[qh][ktp][grpp * 16 + li][(grp & 1) * 4] = o;
      }
    }
  }
  __syncthreads();

  // ---- proj: wave w8 computes out rows w8*32 .. +31, 32 positions ----
  {
    const int Mt0 = w8 * 2;
    const s16x8* __restrict__ Af = (const s16x8*)Wpp;
    f32x4 acc[2][2];
#pragma unroll
    for (int mt = 0; mt < 2; ++mt)
#pragma unroll
      for (int nt = 0; nt < 2; ++nt) acc[mt][nt] = f32x4{0.f, 0.f, 0.f, 0.f};

    s16x8 pa[3][2];
    auto loadA = [&](int kt, s16x8 (&a)[2]) {
#pragma unroll
      for (int mt = 0; mt < 2; ++mt)
        a[mt] = Af[((size_t)(Mt0 + mt) * 8 + kt) * 64 + lane];
    };
    loadA(0, pa[0]);
    loadA(1, pa[1]);
#pragma unroll
    for (int kt = 0; kt < 8; ++kt) {
      if (kt + 2 < 8) loadA(kt + 2, pa[(kt + 2) % 3]);
      s16x8 bb[2];
#pragma unroll
      for (int nt = 0; nt < 2; ++nt)
        bb[nt] = *(const s16x8*)&Ex[nt][kt][lane][0];
#pragma unroll
      for (int mt = 0; mt < 2; ++mt)
#pragma unroll
        for (int nt = 0; nt < 2; ++nt)
          acc[mt][nt] = mfma16(pa[kt % 3][mt], bb[nt], acc[mt][nt]);
    }

#pragma unroll
    for (int mt = 0; mt < 2; ++mt) {
      const int mbase = w8 * 32 + mt * 16 + 4 * grp;
      const float4 bv = *(const float4*)(bpj + mbase);
      const float bvr[4] = {bv.x, bv.y, bv.z, bv.w};
#pragma unroll
      for (int nt = 0; nt < 2; ++nt) {
        const int pos = pb * 32 + nt * 16 + li;
#pragma unroll
        for (int r2 = 0; r2 < 4; ++r2) {
          const size_t ob = ((size_t)(b * 256 + mbase + r2)) * 1024 + pos;
          out[ob] = acc[mt][nt][r2] + bvr[r2] + x[ob];
        }
      }
    }
  }
}

// ---------------------------------------------------------------------------
extern "C" void kernel_launch(void* const* d_in, const int* in_sizes, int n_in,
                              void* d_out, int out_size, void* d_ws, size_t ws_size,
                              hipStream_t stream) {
  const float* x      = (const float*)d_in[0];
  const float* gamma  = (const float*)d_in[1];
  const float* beta   = (const float*)d_in[2];
  const float* w_qkv  = (const float*)d_in[3];
  const float* b_qkv  = (const float*)d_in[4];
  const float* w_proj = (const float*)d_in[5];
  const float* b_proj = (const float*)d_in[6];
  float* out = (float*)d_out;

  unsigned short* ws = (unsigned short*)d_ws;
  unsigned short* Wqp  = ws;                    // 196608
  unsigned short* Wpp  = Wqp + 196608;          // 65536
  unsigned short* hTp  = Wpp + 65536;           // 2097152
  unsigned short* Qp   = hTp + 2097152;         // 2097152
  unsigned short* Kp   = Qp + 2097152;          // 2097152
  unsigned short* Vp   = Kp + 2097152;          // 2097152 (+2MB slack after)
  unsigned* cnt = (unsigned*)(Vp + 2097152 + 1048576);   // 32 B, past slack

  hipMemsetAsync(cnt, 0, 8 * sizeof(unsigned), stream);
  hipLaunchKernelGGL(prep_kernel, dim3(384), dim3(256), 0, stream,
                     x, gamma, beta, hTp, w_qkv, w_proj, Wqp, Wpp);
  hipLaunchKernelGGL(fused_kernel, dim3(256), dim3(512), 0, stream,
                     Wqp, b_qkv, hTp, Qp, Kp, Vp, Wpp, b_proj, x, out, cnt);
}

// Round 18
// 35.780 us; speedup vs baseline: 1.2474x; 1.2474x over previous
//
#include <hip/hip_runtime.h>
#include <hip/hip_bf16.h>

static constexpr int kC = 256;
static constexpr int kN = 1024;   // H*W

using s16x8 = __attribute__((ext_vector_type(8))) short;
using f32x4 = __attribute__((ext_vector_type(4))) float;
using u32x4 = __attribute__((ext_vector_type(4))) unsigned int;

__device__ inline f32x4 mfma16(s16x8 a, s16x8 b, f32x4 c) {
  return __builtin_amdgcn_mfma_f32_16x16x32_bf16(a, b, c, 0, 0, 0);
}

__device__ inline unsigned short f2bf(float f) {   // RNE
  unsigned u = __builtin_bit_cast(unsigned, f);
  u = (u + 0x7fffu + ((u >> 16) & 1u)) >> 16;
  return (unsigned short)u;
}

__device__ inline float exp2_fast(float x) {   // 2^x, single v_exp_f32
  float r;
  asm("v_exp_f32 %0, %1" : "=v"(r) : "v"(x));
  return r;
}

__device__ inline unsigned cvt_pk_bf16(float lo, float hi) {
  unsigned r;
  asm("v_cvt_pk_bf16_f32 %0, %1, %2" : "=v"(r) : "v"(lo), "v"(hi));
  return r;
}

// 1/sqrt(64) * log2(e): folded into Q so QK^T lands in exp2 units.
static constexpr float kQScale = 0.18033688011112042f;

// ---------------------------------------------------------------------------
// prep: blocks 0..127 pack weights into A-frag layout; blocks 128..383 GN.
// ---------------------------------------------------------------------------
__global__ __launch_bounds__(256) void prep_kernel(
    const float* __restrict__ x, const float* __restrict__ gamma,
    const float* __restrict__ beta, unsigned short* __restrict__ hTp,
    const float* __restrict__ wq, const float* __restrict__ wp,
    unsigned short* __restrict__ Wqp, unsigned short* __restrict__ Wpp) {
  if (blockIdx.x < 128) {
    const int tid = blockIdx.x * 256 + threadIdx.x;   // 0..32767
    const float* src;
    unsigned short* dst;
    if (tid < 24576) {
      const int fragid = tid >> 6, lane = tid & 63;
      const int Mt = fragid >> 3, kt = fragid & 7;
      src = wq + (size_t)(Mt * 16 + (lane & 15)) * 256 + kt * 32 + (lane >> 4) * 8;
      dst = Wqp + (size_t)tid * 8;
    } else {
      const int id = tid - 24576;
      const int fragid = id >> 6, lane = id & 63;
      const int Mt = fragid >> 3, kt = fragid & 7;
      src = wp + (size_t)(Mt * 16 + (lane & 15)) * 256 + kt * 32 + (lane >> 4) * 8;
      dst = Wpp + (size_t)id * 8;
    }
    const float4 f0 = *(const float4*)src;
    const float4 f1 = *(const float4*)(src + 4);
    ushort4 o0, o1;
    o0.x = f2bf(f0.x); o0.y = f2bf(f0.y); o0.z = f2bf(f0.z); o0.w = f2bf(f0.w);
    o1.x = f2bf(f1.x); o1.y = f2bf(f1.y); o1.z = f2bf(f1.z); o1.w = f2bf(f1.w);
    *(ushort4*)dst = o0;
    *(ushort4*)(dst + 4) = o1;
    return;
  }

  const int bg = blockIdx.x - 128;
  const int b = bg & 7, g = bg >> 3;   // batch = XCD
  const size_t base = ((size_t)b * kC + (size_t)g * 8) * kN;
  const float4* __restrict__ x4 = (const float4*)(x + base);
  const int t = threadIdx.x;

  float vv[8][4];
  float s = 0.f, ss = 0.f;
#pragma unroll
  for (int i = 0; i < 8; ++i) {
    const float4 v = x4[t + 256 * i];
    vv[i][0] = v.x; vv[i][1] = v.y; vv[i][2] = v.z; vv[i][3] = v.w;
    s += v.x + v.y + v.z + v.w;
    ss += v.x * v.x + v.y * v.y + v.z * v.z + v.w * v.w;
  }
#pragma unroll
  for (int off = 32; off > 0; off >>= 1) {
    s += __shfl_xor(s, off);
    ss += __shfl_xor(ss, off);
  }
  __shared__ float rs[4], rss[4];
  const int wave = t >> 6, lane = t & 63;
  if (lane == 0) { rs[wave] = s; rss[wave] = ss; }
  __syncthreads();
  s = rs[0] + rs[1] + rs[2] + rs[3];
  ss = rss[0] + rss[1] + rss[2] + rss[3];
  const float mean = s * (1.f / 8192.f);
  const float var = ss * (1.f / 8192.f) - mean * mean;
  const float rinv = rsqrtf(var + 1e-5f);
  float ga[8], be[8];
#pragma unroll
  for (int i = 0; i < 8; ++i) {
    ga[i] = gamma[g * 8 + i] * rinv;
    be[i] = beta[g * 8 + i] - mean * ga[i];
  }
  const int kt = g >> 2, gq = g & 3;
#pragma unroll
  for (int r = 0; r < 4; ++r) {
    const int pos = 4 * t + r;
    const int nt = pos >> 4, lp = pos & 15;
    unsigned short* dst =
        hTp + ((size_t)((b * 64 + nt) * 8 + kt) * 64 + (gq * 16 + lp)) * 8;
    ushort4 o0, o1;
    o0.x = f2bf(vv[0][r] * ga[0] + be[0]);
    o0.y = f2bf(vv[1][r] * ga[1] + be[1]);
    o0.z = f2bf(vv[2][r] * ga[2] + be[2]);
    o0.w = f2bf(vv[3][r] * ga[3] + be[3]);
    o1.x = f2bf(vv[4][r] * ga[4] + be[4]);
    o1.y = f2bf(vv[5][r] * ga[5] + be[5]);
    o1.z = f2bf(vv[6][r] * ga[6] + be[6]);
    o1.w = f2bf(vv[7][r] * ga[7] + be[7]);
    *(ushort4*)dst = o0;
    *(ushort4*)(dst + 4) = o1;
  }
}

// ---------------------------------------------------------------------------
// LDS-free bf16 MFMA QKV GEMM, depth-3 register prefetch (4 rotating slots).
// V stored sigma-permuted so attention's P registers are directly the PV
// B-frag (no LDS round trip).
// ---------------------------------------------------------------------------
__device__ inline void gload(const s16x8* __restrict__ Af,
                             const s16x8* __restrict__ Bf,
                             int Mt0, int Nt0, int kt, int lane,
                             s16x8 (&a)[4], s16x8 (&bb)[2]) {
#pragma unroll
  for (int mt = 0; mt < 4; ++mt)
    a[mt] = Af[((size_t)(Mt0 + mt) * 8 + kt) * 64 + lane];
#pragma unroll
  for (int nt = 0; nt < 2; ++nt)
    bb[nt] = Bf[((size_t)(Nt0 + nt) * 8 + kt) * 64 + lane];
}

__device__ inline void gmfma(const s16x8 (&a)[4], const s16x8 (&bb)[2],
                             f32x4 (&acc)[4][2], bool swap) {
  if (swap) {
#pragma unroll
    for (int mt = 0; mt < 4; ++mt)
#pragma unroll
      for (int nt = 0; nt < 2; ++nt)
        acc[mt][nt] = mfma16(bb[nt], a[mt], acc[mt][nt]);
  } else {
#pragma unroll
    for (int mt = 0; mt < 4; ++mt)
#pragma unroll
      for (int nt = 0; nt < 2; ++nt)
        acc[mt][nt] = mfma16(a[mt], bb[nt], acc[mt][nt]);
  }
}

__global__ __launch_bounds__(256) void gemm_qkv_kernel(
    const unsigned short* __restrict__ Wp, const float* __restrict__ bias,
    const unsigned short* __restrict__ Bp,
    unsigned short* __restrict__ Qp, unsigned short* __restrict__ Kp,
    unsigned short* __restrict__ Vp) {
  const int bid = blockIdx.x;
  const int swz = (bid & 7) * 96 + (bid >> 3);
  const int b = swz / 96, rr = swz % 96;
  const int mb = rr >> 4, nb = rr & 15;
  const int t = threadIdx.x;
  const int wave = t >> 6, lane = t & 63;
  const int li = lane & 15, grp = lane >> 4;
  const int m0 = mb * 128 + (wave >> 1) * 64;
  const int n0 = nb * 64 + (wave & 1) * 32;
  const bool swap = mb >= 4;   // V tiles
  const int Mt0 = m0 >> 4;
  const int Nt0 = b * 64 + (n0 >> 4);
  const s16x8* __restrict__ Af = (const s16x8*)Wp;
  const s16x8* __restrict__ Bf = (const s16x8*)Bp;

  f32x4 acc[4][2];
#pragma unroll
  for (int mt = 0; mt < 4; ++mt)
#pragma unroll
    for (int nt = 0; nt < 2; ++nt) acc[mt][nt] = f32x4{0.f, 0.f, 0.f, 0.f};

  s16x8 sa[4][4], sb[4][2];   // 4 rotating slots, depth-3 prefetch
  gload(Af, Bf, Mt0, Nt0, 0, lane, sa[0], sb[0]);
  gload(Af, Bf, Mt0, Nt0, 1, lane, sa[1], sb[1]);
  gload(Af, Bf, Mt0, Nt0, 2, lane, sa[2], sb[2]);
#pragma unroll
  for (int kt = 0; kt < 8; ++kt) {
    if (kt + 3 < 8)
      gload(Af, Bf, Mt0, Nt0, kt + 3, lane, sa[(kt + 3) & 3], sb[(kt + 3) & 3]);
    gmfma(sa[kt & 3], sb[kt & 3], acc, swap);
  }

  if (!swap) {
    // Q/K: D rows = ch (4grp+r), cols = pos (li). Q gets kQScale folded in.
    unsigned short* __restrict__ Tp = (mb < 2) ? Qp : Kp;
    const float qs = (mb < 2) ? kQScale : 1.0f;
#pragma unroll
    for (int mt = 0; mt < 4; ++mt) {
      const int mbase = m0 + mt * 16;
      const int head = (mbase >> 6) & 3;
      const int bh = b * 4 + head;
      const int c16 = mbase & 63;
      const int ks = c16 >> 5;
      const int grpp = ((c16 >> 3) + (grp >> 1)) & 3;
      const float4 bv = *(const float4*)(bias + mbase + 4 * grp);
#pragma unroll
      for (int nt = 0; nt < 2; ++nt) {
        const int pt = (n0 >> 4) + nt;
        ushort4 o;
        o.x = f2bf((acc[mt][nt][0] + bv.x) * qs);
        o.y = f2bf((acc[mt][nt][1] + bv.y) * qs);
        o.z = f2bf((acc[mt][nt][2] + bv.z) * qs);
        o.w = f2bf((acc[mt][nt][3] + bv.w) * qs);
        *(ushort4*)(Tp + (size_t)bh * 65536 +
                    ((size_t)(pt * 2 + ks) * 64 + grpp * 16 + li) * 8 +
                    (grp & 1) * 4) = o;
      }
    }
  } else {
    // V: D rows = pos (4grp+r), cols = ch (li); sigma-permuted column store.
#pragma unroll
    for (int mt = 0; mt < 4; ++mt) {
      const int mbase = m0 + mt * 16;
      const int head = (mbase >> 6) & 3;
      const int bh = b * 4 + head;
      const int ct = (mbase & 63) >> 4;
      const float bvc = bias[mbase + li];
      const int kvt = n0 >> 5;
#pragma unroll
      for (int nt = 0; nt < 2; ++nt) {
        ushort4 o;
        o.x = f2bf(acc[mt][nt][0] + bvc);
        o.y = f2bf(acc[mt][nt][1] + bvc);
        o.z = f2bf(acc[mt][nt][2] + bvc);
        o.w = f2bf(acc[mt][nt][3] + bvc);
        *(ushort4*)(Vp + (size_t)bh * 65536 +
                    ((size_t)(ct * 32 + kvt) * 64 + grp * 16 + li) * 8 +
                    nt * 4) = o;
      }
    }
  }
}

// ---------------------------------------------------------------------------
// K-split fused flash-attention + proj, 32 q per wave (2 q-groups share one
// K/V stream -> half the L2 traffic; two independent softmax chains give
// free MFMA/VALU overlap). 256 blocks x 512 threads. Block = (b, 32 pos);
// 8 waves = 4 heads x 2 K-halves; each wave: 16 KV tiles x 32 q.
// Partials merged per head via LDS + exact exp2 rescale, then proj.
// ---------------------------------------------------------------------------
__global__ __launch_bounds__(512) void attn_proj_kernel(
    const unsigned short* __restrict__ Qp, const unsigned short* __restrict__ Kp,
    const unsigned short* __restrict__ Vp, const unsigned short* __restrict__ Wpp,
    const float* __restrict__ bpj, const float* __restrict__ x,
    float* __restrict__ out) {
  __shared__ __align__(16) float Ml[4][2][64][18];           // 36 KB partials
  __shared__ __align__(16) unsigned short Ex[2][8][64][8];   // 16 KB proj B-frags
  const int bid = blockIdx.x;
  const int b = bid & 7;                    // batch = XCD
  const int pb = bid >> 3;                  // 32-position block, 0..31
  const int t = threadIdx.x;
  const int w8 = t >> 6, lane = t & 63;
  const int head = w8 & 3, khalf = w8 >> 2;
  const int li = lane & 15, grp = lane >> 4;
  const int bh = b * 4 + head;
  const unsigned short* __restrict__ Qb = Qp + (size_t)bh * 65536;
  const unsigned short* __restrict__ Kb = Kp + (size_t)bh * 65536;
  const unsigned short* __restrict__ Vb = Vp + (size_t)bh * 65536;

  s16x8 qf[2][2];
#pragma unroll
  for (int qh = 0; qh < 2; ++qh)
#pragma unroll
    for (int ks = 0; ks < 2; ++ks)
      qf[qh][ks] = *(const s16x8*)(Qb + (((pb * 2 + qh) * 2 + ks) * 64 + lane) * 8);

  f32x4 O[2][4];
  f32x4 lvec[2];
  float m_run[2] = {-1.0e30f, -1.0e30f};
#pragma unroll
  for (int qh = 0; qh < 2; ++qh) {
    lvec[qh] = f32x4{0.f, 0.f, 0.f, 0.f};
#pragma unroll
    for (int ct = 0; ct < 4; ++ct) O[qh][ct] = f32x4{0.f, 0.f, 0.f, 0.f};
  }
  const int kbase = khalf * 16;

  auto loadK = [&](int it, s16x8 (&kk)[2][2]) {
#pragma unroll
    for (int mt = 0; mt < 2; ++mt)
#pragma unroll
      for (int ks = 0; ks < 2; ++ks)
        kk[mt][ks] = *(const s16x8*)(
            Kb + ((size_t)((it * 2 + mt) * 2 + ks) * 64 + lane) * 8);
  };
  auto loadV = [&](int it, s16x8 (&vv)[4]) {
#pragma unroll
    for (int ct = 0; ct < 4; ++ct)
      vv[ct] = *(const s16x8*)(Vb + ((size_t)(ct * 32 + it) * 64 + lane) * 8);
  };

  // one KV tile for BOTH q-groups (dual independent softmax chains)
  auto body = [&](const s16x8 (&kk)[2][2], const s16x8 (&vv)[4]) {
    f32x4 s[2][2];
    __builtin_amdgcn_s_setprio(1);
#pragma unroll
    for (int qh = 0; qh < 2; ++qh)
#pragma unroll
      for (int mt = 0; mt < 2; ++mt) {
        s[qh][mt] = mfma16(kk[mt][0], qf[qh][0], f32x4{0.f, 0.f, 0.f, 0.f});
        s[qh][mt] = mfma16(kk[mt][1], qf[qh][1], s[qh][mt]);
      }
    __builtin_amdgcn_s_setprio(0);
#pragma unroll
    for (int qh = 0; qh < 2; ++qh) {
      const float A = fmaxf(fmaxf(s[qh][0][0], s[qh][0][1]), s[qh][0][2]);
      const float B = fmaxf(fmaxf(s[qh][0][3], s[qh][1][0]), s[qh][1][1]);
      const float C = fmaxf(fmaxf(s[qh][1][2], s[qh][1][3]), A);
      float pm = fmaxf(B, C);
      pm = fmaxf(pm, __shfl_xor(pm, 16));
      pm = fmaxf(pm, __shfl_xor(pm, 32));
      if (!__all(pm <= m_run[qh] + 8.0f)) {   // defer-max rescale (exp2 units)
        const float mnew = fmaxf(m_run[qh], pm);
        const float f = exp2_fast(m_run[qh] - mnew);
        m_run[qh] = mnew;
        lvec[qh] *= f;
#pragma unroll
        for (int ct = 0; ct < 4; ++ct) O[qh][ct] *= f;
      }
      f32x4 p[2];
#pragma unroll
      for (int mt = 0; mt < 2; ++mt) {
#pragma unroll
        for (int r = 0; r < 4; ++r) p[mt][r] = exp2_fast(s[qh][mt][r] - m_run[qh]);
        lvec[qh] += p[mt];
      }
      u32x4 pk;
      pk[0] = cvt_pk_bf16(p[0][0], p[0][1]);
      pk[1] = cvt_pk_bf16(p[0][2], p[0][3]);
      pk[2] = cvt_pk_bf16(p[1][0], p[1][1]);
      pk[3] = cvt_pk_bf16(p[1][2], p[1][3]);
      const s16x8 pf = __builtin_bit_cast(s16x8, pk);
      __builtin_amdgcn_s_setprio(1);
#pragma unroll
      for (int ct = 0; ct < 4; ++ct) O[qh][ct] = mfma16(vv[ct], pf, O[qh][ct]);
      __builtin_amdgcn_s_setprio(0);
    }
  };

  {
    s16x8 k0[2][2], k1[2][2], v0[4], v1[4];
    loadK(kbase, k0);
    loadV(kbase, v0);
    // Tail overreads (it = kbase+16) land in the next bh's region or the
    // allocated slack after Vp — computed but never consumed.
#pragma unroll 1
    for (int h2 = 0; h2 < 8; ++h2) {
      const int it = kbase + 2 * h2;
      loadK(it + 1, k1);
      loadV(it + 1, v1);
      body(k0, v0);
      loadK(it + 2, k0);
      loadV(it + 2, v0);
      body(k1, v1);
    }
  }

  // per-q l over this wave's K-half (per q = li, replicated across grp)
  float lt[2];
#pragma unroll
  for (int qh = 0; qh < 2; ++qh) {
    lt[qh] = lvec[qh][0] + lvec[qh][1] + lvec[qh][2] + lvec[qh][3];
    lt[qh] += __shfl_xor(lt[qh], 16);
    lt[qh] += __shfl_xor(lt[qh], 32);
  }

  // ---- merge K-halves per head ----
  if (khalf == 1) {
#pragma unroll
    for (int qh = 0; qh < 2; ++qh) {
      float* dst = &Ml[head][qh][lane][0];
#pragma unroll
      for (int ct = 0; ct < 4; ++ct) *(f32x4*)(dst + ct * 4) = O[qh][ct];
      dst[16] = m_run[qh];
      dst[17] = lt[qh];
    }
  }
  __syncthreads();
  if (khalf == 0) {
#pragma unroll
    for (int qh = 0; qh < 2; ++qh) {
      const float* src = &Ml[head][qh][lane][0];
      const float mB = src[16], lB = src[17];
      const float mS = fmaxf(m_run[qh], mB);
      const float fA = exp2_fast(m_run[qh] - mS);
      const float fB = exp2_fast(mB - mS);
      const float rinv = 1.f / (lt[qh] * fA + lB * fB);
      const float a = fA * rinv, bs = fB * rinv;
#pragma unroll
      for (int ct = 0; ct < 4; ++ct) {
        const f32x4 ob = *(const f32x4*)(src + ct * 4);
        ushort4 o;
        o.x = f2bf(O[qh][ct][0] * a + ob[0] * bs);
        o.y = f2bf(O[qh][ct][1] * a + ob[1] * bs);
        o.z = f2bf(O[qh][ct][2] * a + ob[2] * bs);
        o.w = f2bf(O[qh][ct][3] * a + ob[3] * bs);
        const int ktp = head * 2 + (ct >> 1);
        const int grpp = ((ct & 1) * 2 + (grp >> 1)) & 3;
        *(ushort4*)&Ex[qh][ktp][grpp * 16 + li][(grp & 1) * 4] = o;
      }
    }
  }
  __syncthreads();

  // ---- proj: wave w8 computes out rows w8*32 .. +31, 32 positions ----
  {
    const int Mt0 = w8 * 2;
    const s16x8* __restrict__ Af = (const s16x8*)Wpp;
    f32x4 acc[2][2];
#pragma unroll
    for (int mt = 0; mt < 2; ++mt)
#pragma unroll
      for (int nt = 0; nt < 2; ++nt) acc[mt][nt] = f32x4{0.f, 0.f, 0.f, 0.f};

    s16x8 pa[3][2];
    auto loadA = [&](int kt, s16x8 (&a)[2]) {
#pragma unroll
      for (int mt = 0; mt < 2; ++mt)
        a[mt] = Af[((size_t)(Mt0 + mt) * 8 + kt) * 64 + lane];
    };
    loadA(0, pa[0]);
    loadA(1, pa[1]);
#pragma unroll
    for (int kt = 0; kt < 8; ++kt) {
      if (kt + 2 < 8) loadA(kt + 2, pa[(kt + 2) % 3]);
      s16x8 bb[2];
#pragma unroll
      for (int nt = 0; nt < 2; ++nt)
        bb[nt] = *(const s16x8*)&Ex[nt][kt][lane][0];
#pragma unroll
      for (int mt = 0; mt < 2; ++mt)
#pragma unroll
        for (int nt = 0; nt < 2; ++nt)
          acc[mt][nt] = mfma16(pa[kt % 3][mt], bb[nt], acc[mt][nt]);
    }

#pragma unroll
    for (int mt = 0; mt < 2; ++mt) {
      const int mbase = w8 * 32 + mt * 16 + 4 * grp;
      const float4 bv = *(const float4*)(bpj + mbase);
      const float bvr[4] = {bv.x, bv.y, bv.z, bv.w};
#pragma unroll
      for (int nt = 0; nt < 2; ++nt) {
        const int pos = pb * 32 + nt * 16 + li;
#pragma unroll
        for (int r2 = 0; r2 < 4; ++r2) {
          const size_t ob = ((size_t)(b * 256 + mbase + r2)) * 1024 + pos;
          out[ob] = acc[mt][nt][r2] + bvr[r2] + x[ob];
        }
      }
    }
  }
}

// ---------------------------------------------------------------------------
extern "C" void kernel_launch(void* const* d_in, const int* in_sizes, int n_in,
                              void* d_out, int out_size, void* d_ws, size_t ws_size,
                              hipStream_t stream) {
  const float* x      = (const float*)d_in[0];
  const float* gamma  = (const float*)d_in[1];
  const float* beta   = (const float*)d_in[2];
  const float* w_qkv  = (const float*)d_in[3];
  const float* b_qkv  = (const float*)d_in[4];
  const float* w_proj = (const float*)d_in[5];
  const float* b_proj = (const float*)d_in[6];
  float* out = (float*)d_out;

  unsigned short* ws = (unsigned short*)d_ws;
  unsigned short* Wqp  = ws;                    // 196608
  unsigned short* Wpp  = Wqp + 196608;          // 65536
  unsigned short* hTp  = Wpp + 65536;           // 2097152
  unsigned short* Qp   = hTp + 2097152;         // 2097152
  unsigned short* Kp   = Qp + 2097152;          // 2097152
  unsigned short* Vp   = Kp + 2097152;          // 2097152 (+slack after for overreads)

  hipLaunchKernelGGL(prep_kernel, dim3(384), dim3(256), 0, stream,
                     x, gamma, beta, hTp, w_qkv, w_proj, Wqp, Wpp);
  hipLaunchKernelGGL(gemm_qkv_kernel, dim3(768), dim3(256), 0, stream,
                     Wqp, b_qkv, hTp, Qp, Kp, Vp);
  hipLaunchKernelGGL(attn_proj_kernel, dim3(256), dim3(512), 0, stream,
                     Qp, Kp, Vp, Wpp, b_proj, x, out);
}